// Round 11
// baseline (178.264 us; speedup 1.0000x reference)
//
#include <hip/hip_runtime.h>
#include <hip/hip_bf16.h>

#define FDIM 80
#define RDIM 20
#define LDP  104     // LDS row stride (bf16)
#define WROW 96      // Wt row stride (bf16), K padded to 96
#define AROWS 32     // atoms per block in atom_mfma

#define NBUCK 512    // buckets of 32 atoms
#define BCAP  2048   // records per bucket (mean 1536, sigma ~39 -> +13 sigma)
#define CHUNK 4096   // entries per binA block
#define RECW  12     // u32 words per record (48B)

#define RSLOT 5              // fallback: u64 slots/atom (13-bit fields)
#define FIX_SCALE 64.0f
#define FIX_INV   0.015625f

typedef float  f32x4  __attribute__((ext_vector_type(4)));
typedef short  bf16x8 __attribute__((ext_vector_type(8)));

__device__ __forceinline__ float sp_f(float x){
  float e = __expf(-fabsf(x));
  return fmaxf(x, 0.f) + __logf(1.f + e);
}
__device__ __forceinline__ __hip_bfloat16 tob(float x){ return __float2bfloat16(x); }

__device__ __forceinline__ unsigned bf16r(float f){
  unsigned u = __float_as_uint(f);
  return (u + 0x7fffu + ((u >> 16) & 1u)) >> 16;
}
__device__ __forceinline__ unsigned pk2(float x, float y){
  return (bf16r(y) << 16) | bf16r(x);
}

// ---------------------------------------------------------------------------
// Weight prep: Wt[slot][j][k] = bf16(W[k][j]), zero-padded k in [80,96)
// ---------------------------------------------------------------------------
struct WPtrs { const float* p[21]; };

__global__ __launch_bounds__(256) void prep_weights(WPtrs wp, __hip_bfloat16* __restrict__ wt){
  const float* W = wp.p[blockIdx.x];
  __hip_bfloat16* dst = wt + (size_t)blockIdx.x * FDIM * WROW;
  for (int i = threadIdx.x; i < FDIM * WROW; i += 256){
    int j = i / WROW, k = i - j * WROW;
    dst[i] = __float2bfloat16(k < FDIM ? W[k * FDIM + j] : 0.f);
  }
}

// ---------------------------------------------------------------------------
// Pass A: bin (pair,side) entries by atom bucket, write 48B records
// record = [local_atom, 10 x u32 (2xbf16 aev), pad]
// ---------------------------------------------------------------------------
__global__ __launch_bounds__(256) void binA(
    const float* __restrict__ aev, const int* __restrict__ idx12,
    int* __restrict__ gcursor, unsigned int* __restrict__ rec, int P)
{
  __shared__ int a_arr[CHUNK];
  __shared__ unsigned int grp[CHUNK];
  __shared__ unsigned short grpb[CHUNK];
  __shared__ int cnt[NBUCK], cnt2[NBUCK], boff[NBUCK], gbase[NBUCK];
  __shared__ int scanp[256];

  const int t  = threadIdx.x;
  const int c0 = blockIdx.x * CHUNK;

  for (int b = t; b < NBUCK; b += 256){ cnt[b] = 0; cnt2[b] = 0; }
  __syncthreads();
  #pragma unroll
  for (int k = 0; k < CHUNK / 256; k++){
    int i = k * 256 + t;
    int a = idx12[c0 + i];
    a_arr[i] = a;
    atomicAdd(&cnt[a >> 5], 1);
  }
  __syncthreads();
  // exclusive scan over 512 bins (2 bins/thread + Hillis-Steele on partials)
  int cv0 = cnt[2*t], cv1 = cnt[2*t + 1];
  scanp[t] = cv0 + cv1;
  __syncthreads();
  for (int off = 1; off < 256; off <<= 1){
    int v = (t >= off) ? scanp[t - off] : 0;
    __syncthreads();
    scanp[t] += v;
    __syncthreads();
  }
  int ex = (t == 0) ? 0 : scanp[t - 1];
  boff[2*t] = ex; boff[2*t + 1] = ex + cv0;
  for (int b = t; b < NBUCK; b += 256)
    gbase[b] = atomicAdd(&gcursor[b], cnt[b]);
  __syncthreads();
  // group entries by bucket in LDS
  #pragma unroll
  for (int k = 0; k < CHUNK / 256; k++){
    int i = k * 256 + t;
    int a = a_arr[i];
    int b = a >> 5;
    int e = c0 + i;
    unsigned int p = (e < P) ? (unsigned)e : (unsigned)(e - P);
    int slot = boff[b] + atomicAdd(&cnt2[b], 1);
    grp[slot]  = (p << 5) | (unsigned)(a & 31);
    grpb[slot] = (unsigned short)b;
  }
  __syncthreads();
  // write records: consecutive slots -> consecutive record addresses per bucket
  #pragma unroll
  for (int k = 0; k < CHUNK / 256; k++){
    int slot = k * 256 + t;
    unsigned int gv = grp[slot];
    int b = grpb[slot];
    unsigned int p = gv >> 5;
    unsigned int local = gv & 31u;
    int off = gbase[b] + (slot - boff[b]);
    if (off >= BCAP) continue;   // 13-sigma guard
    const float4* ar = (const float4*)(aev + (size_t)p * RDIM);
    float4 a0 = ar[0], a1 = ar[1], a2 = ar[2], a3 = ar[3], a4 = ar[4];
    uint4 w0, w1, w2;
    w0.x = local;
    w0.y = pk2(a0.x, a0.y); w0.z = pk2(a0.z, a0.w); w0.w = pk2(a1.x, a1.y);
    w1.x = pk2(a1.z, a1.w); w1.y = pk2(a2.x, a2.y); w1.z = pk2(a2.z, a2.w); w1.w = pk2(a3.x, a3.y);
    w2.x = pk2(a3.z, a3.w); w2.y = pk2(a4.x, a4.y); w2.z = pk2(a4.z, a4.w); w2.w = 0;
    uint4* dst = (uint4*)(rec + ((size_t)b * BCAP + off) * RECW);
    dst[0] = w0; dst[1] = w1; dst[2] = w2;
  }
}

// ---------------------------------------------------------------------------
// Pass B: per-bucket LDS accumulation (no global atomics), write Rf[N][21]
// ---------------------------------------------------------------------------
__global__ __launch_bounds__(256) void accumB(
    const unsigned int* __restrict__ rec, const int* __restrict__ gcursor,
    float* __restrict__ Rf)
{
  __shared__ float Racc[32][21];   // 21 coprime 32 -> conflict-free banks
  const int t = threadIdx.x;
  const int b = blockIdx.x;

  for (int i = t; i < 32 * 21; i += 256) ((float*)Racc)[i] = 0.f;
  __syncthreads();

  const int cntb = min(gcursor[b], BCAP);
  const unsigned int* rb = rec + (size_t)b * BCAP * RECW;
  const int rloc = t >> 5;   // 8 records in flight
  const int c    = t & 31;

  for (int r0 = 0; r0 < cntb; r0 += 8){
    int r = r0 + rloc;
    if (r < cntb){
      const unsigned int* rp = rb + (size_t)r * RECW;
      int local = (int)rp[0];
      if (c < 20){
        unsigned w = rp[1 + (c >> 1)];
        unsigned h = (c & 1) ? (w >> 16) : (w & 0xffffu);
        atomicAdd(&Racc[local][c], __uint_as_float(h << 16));
      } else if (c == 20){
        atomicAdd(&Racc[local][20], 1.f);
      }
    }
  }
  __syncthreads();
  for (int i = t; i < 32 * 21; i += 256)
    Rf[(size_t)b * (32 * 21) + i] = ((float*)Racc)[i];
}

// ---------------------------------------------------------------------------
// Fallback: u64 packed atomic scatter (proven 57us) + convert to Rf
// ---------------------------------------------------------------------------
__global__ __launch_bounds__(256) void scatter_p13(const float* __restrict__ aev,
    const int* __restrict__ idx12, unsigned long long* __restrict__ R5u, int P)
{
  int g = blockIdx.x * 256 + threadIdx.x;
  if (g >= P * RSLOT) return;
  int p = g / RSLOT, s = g - p * RSLOT;
  float4 a = ((const float4*)(aev + (size_t)p * RDIM))[s];
  unsigned long long f0 = (unsigned long long)__float2uint_rn(a.x * FIX_SCALE);
  unsigned long long f1 = (unsigned long long)__float2uint_rn(a.y * FIX_SCALE);
  unsigned long long f2 = (unsigned long long)__float2uint_rn(a.z * FIX_SCALE);
  unsigned long long f3 = (unsigned long long)__float2uint_rn(a.w * FIX_SCALE);
  unsigned long long v = f0 | (f1 << 13) | (f2 << 26) | (f3 << 39);
  if (s == 0) v |= (1ULL << 52);
  int i1 = idx12[p], i2 = idx12[P + p];
  atomicAdd(&R5u[(size_t)i1 * RSLOT + s], v);
  atomicAdd(&R5u[(size_t)i2 * RSLOT + s], v);
}

__global__ __launch_bounds__(256) void conv_p13(
    const unsigned long long* __restrict__ R5u, float* __restrict__ Rf, int N)
{
  int n = blockIdx.x * 256 + threadIdx.x;
  if (n >= N) return;
  #pragma unroll
  for (int s = 0; s < RSLOT; s++){
    unsigned long long v = R5u[(size_t)n * RSLOT + s];
    #pragma unroll
    for (int f = 0; f < 4; f++)
      Rf[(size_t)n * 21 + 4*s + f] = (float)((unsigned)(v >> (13*f)) & 0x1fffu) * FIX_INV;
    if (s == 0) Rf[(size_t)n * 21 + RDIM] = (float)((unsigned)(v >> 52) & 0xfffu);
  }
}

// ---------------------------------------------------------------------------
// Atom path (R8 structure): 32 atoms/block, 5 waves, rolling WF prefetch,
// S fused in-kernel from Rf.
// ---------------------------------------------------------------------------
struct WF { bf16x8 b0, b1, b2; float bias; };

__device__ __forceinline__ WF loadWF(const __hip_bfloat16* __restrict__ wb,
                                     int slot, const float* __restrict__ bias, int row){
  WF w;
  const __hip_bfloat16* p = wb + (size_t)slot * (FDIM * WROW);
  w.b0 = *(const bf16x8*)(const void*)(p);
  w.b1 = *(const bf16x8*)(const void*)(p + 32);
  w.b2 = *(const bf16x8*)(const void*)(p + 64);
  w.bias = bias[row];
  return w;
}

__device__ __forceinline__ void mfmaL(f32x4 acc[2],
    const __hip_bfloat16 (*in)[LDP], int j0, int kb, const WF& w)
{
  #pragma unroll
  for (int s = 0; s < 2; s++){
    const __hip_bfloat16* ap = &in[16*s + j0][kb];
    bf16x8 a0 = *(const bf16x8*)(const void*)(ap);
    bf16x8 a1 = *(const bf16x8*)(const void*)(ap + 32);
    bf16x8 a2 = *(const bf16x8*)(const void*)(ap + 64);
    acc[s] = (f32x4){w.bias, w.bias, w.bias, w.bias};
    acc[s] = __builtin_amdgcn_mfma_f32_16x16x32_bf16(a0, w.b0, acc[s], 0, 0, 0);
    acc[s] = __builtin_amdgcn_mfma_f32_16x16x32_bf16(a1, w.b1, acc[s], 0, 0, 0);
    acc[s] = __builtin_amdgcn_mfma_f32_16x16x32_bf16(a2, w.b2, acc[s], 0, 0, 0);
  }
}

__device__ __forceinline__ void resblk(f32x4 cur[2],
    __hip_bfloat16 (*bA)[LDP], __hip_bfloat16 (*bB)[LDP],
    int j0, int kb, int g, int col,
    WF& w1, WF& w2,
    const __hip_bfloat16* __restrict__ wb, int row,
    int pf1, const float* __restrict__ pf1b,
    int pf2, const float* __restrict__ pf2b)
{
  f32x4 acc[2];
  mfmaL(acc, bA, j0, kb, w1);
  w1 = loadWF(wb, pf1, pf1b, row);
  #pragma unroll
  for (int s = 0; s < 2; s++){
    int r0 = 16*s + g*4;
    #pragma unroll
    for (int i = 0; i < 4; i++) bB[r0 + i][col] = tob(sp_f(acc[s][i]));
  }
  __syncthreads();
  mfmaL(acc, bB, j0, kb, w2);
  w2 = loadWF(wb, pf2, pf2b, row);
  #pragma unroll
  for (int s = 0; s < 2; s++){
    int r0 = 16*s + g*4;
    #pragma unroll
    for (int i = 0; i < 4; i++){
      cur[s][i] = sp_f(acc[s][i] + cur[s][i]);
      bA[r0 + i][col] = tob(cur[s][i]);
    }
  }
  __syncthreads();
}

__global__ __launch_bounds__(320, 4) void atom_mfma(
    const int*   __restrict__ species,
    const float* __restrict__ features,
    const float* __restrict__ Rf,
    const __hip_bfloat16* __restrict__ wt,
    const float* __restrict__ Wg, const float* __restrict__ bg,
    const float* __restrict__ bJ, const float* __restrict__ bI,
    const float* __restrict__ ib1, const float* __restrict__ ib2,
    const float* __restrict__ gate, const float* __restrict__ bint,
    const float* __restrict__ ab1, const float* __restrict__ ab2,
    const float* __restrict__ ob1, const float* __restrict__ ob2,
    const float* __restrict__ Wout, const float* __restrict__ bout,
    float* __restrict__ out_e, float* __restrict__ out_f)
{
  __shared__ __align__(16) __hip_bfloat16 bufA[AROWS][LDP];
  __shared__ __align__(16) __hip_bfloat16 bufB[AROWS][LDP];
  __shared__ __align__(16) __hip_bfloat16 xfb[AROWS][LDP];
  __shared__ float Rl[AROWS][22];
  __shared__ float mskl[AROWS];
  __shared__ float evp[5][AROWS];

  const int t    = threadIdx.x;
  const int lane = t & 63;
  const int nt   = t >> 6;
  const int base = blockIdx.x * AROWS;

  const int j0  = lane & 15;
  const int g   = lane >> 4;
  const int kb  = g * 8;
  const int col = 16*nt + j0;
  const int row = col;
  const __hip_bfloat16* wb = wt + (size_t)row * WROW + kb;

  float wgc[RDIM + 1];
  #pragma unroll
  for (int r = 0; r < RDIM; r++) wgc[r] = Wg[r * FDIM + col];
  wgc[RDIM] = bg[col];

  for (int i = t; i < AROWS * FDIM; i += 320){
    int rr = i / FDIM, cc = i - rr * FDIM;
    float v = features[(size_t)(base + rr) * FDIM + cc];
    xfb [rr][cc] = tob(v);
    bufA[rr][cc] = tob(sp_f(v));
  }
  for (int i = t; i < 3 * AROWS * 16; i += 320){
    int b = i / (AROWS * 16), rem = i % (AROWS * 16);
    int rr = rem >> 4, cc = FDIM + (rem & 15);
    if      (b == 0) bufA[rr][cc] = tob(0.f);
    else if (b == 1) bufB[rr][cc] = tob(0.f);
    else             xfb [rr][cc] = tob(0.f);
  }
  for (int i = t; i < AROWS * 21; i += 320){
    int u = i / 21, r = i - u * 21;
    Rl[u][r] = Rf[(size_t)base * 21 + i];
  }
  if (t < AROWS) mskl[t] = (species[base + t] != -1) ? 1.f : 0.f;
  __syncthreads();

  // S in registers
  f32x4 Sreg[2];
  #pragma unroll
  for (int s = 0; s < 2; s++){
    #pragma unroll
    for (int i = 0; i < 4; i++){
      int rr = 16*s + g*4 + i;
      float a = 0.f;
      #pragma unroll
      for (int r = 0; r <= RDIM; r++) a += Rl[rr][r] * wgc[r];
      Sreg[s][i] = a;
    }
  }

  f32x4 cur[2];

  // proto = sp(sp(f)@WJ+bJ) * S + (f@WI+bI)*mask
  {
    WF wA = loadWF(wb, 0, bJ, row);
    WF wB = loadWF(wb, 1, bI, row);
    f32x4 aJ[2], aI[2];
    mfmaL(aJ, bufA, j0, kb, wA);  wA = loadWF(wb, 3, ib1, row);
    mfmaL(aI, xfb , j0, kb, wB);  wB = loadWF(wb, 4, ib2, row);
    __syncthreads();
    #pragma unroll
    for (int s = 0; s < 2; s++){
      int r0 = 16*s + g*4;
      #pragma unroll
      for (int i = 0; i < 4; i++){
        cur[s][i] = sp_f(aJ[s][i]) * Sreg[s][i] + aI[s][i] * mskl[r0 + i];
        bufA[r0 + i][col] = tob(cur[s][i]);
      }
    }
    __syncthreads();

    resblk(cur, bufA, bufB, j0, kb, g, col, wA, wB, wb, row,
           5, ib1 + FDIM,     6, ib2 + FDIM);
    resblk(cur, bufA, bufB, j0, kb, g, col, wA, wB, wb, row,
           7, ib1 + 2*FDIM,   8, ib2 + 2*FDIM);
    resblk(cur, bufA, bufB, j0, kb, g, col, wA, wB, wb, row,
           2, bint,           9, ab1);

    // nd = f*gate + sp(message)@Wint + bint
    #pragma unroll
    for (int s = 0; s < 2; s++){
      int r0 = 16*s + g*4;
      #pragma unroll
      for (int i = 0; i < 4; i++) bufB[r0 + i][col] = tob(sp_f(cur[s][i]));
    }
    __syncthreads();
    {
      f32x4 acc[2];
      mfmaL(acc, bufB, j0, kb, wA);
      wA = loadWF(wb, 10, ab2, row);
      float gj = gate[col];
      #pragma unroll
      for (int s = 0; s < 2; s++){
        int r0 = 16*s + g*4;
        #pragma unroll
        for (int i = 0; i < 4; i++){
          float xv = __bfloat162float(xfb[r0 + i][col]);
          cur[s][i] = xv * gj + acc[s][i];
          bufA[r0 + i][col] = tob(cur[s][i]);
        }
      }
    }
    __syncthreads();

    resblk(cur, bufA, bufB, j0, kb, g, col, wB, wA, wb, row,
           11, ab1 + FDIM,    12, ab2 + FDIM);
    resblk(cur, bufA, bufB, j0, kb, g, col, wB, wA, wb, row,
           13, ab1 + 2*FDIM,  14, ab2 + 2*FDIM);
    resblk(cur, bufA, bufB, j0, kb, g, col, wB, wA, wb, row,
           15, ob1,           16, ob2);

    // out_features = nd * mask
    #pragma unroll
    for (int s = 0; s < 2; s++){
      int r0 = 16*s + g*4;
      #pragma unroll
      for (int i = 0; i < 4; i++)
        out_f[(size_t)(base + r0 + i) * FDIM + col] = cur[s][i] * mskl[r0 + i];
    }

    resblk(cur, bufA, bufB, j0, kb, g, col, wB, wA, wb, row,
           17, ob1 + FDIM,    18, ob2 + FDIM);
    resblk(cur, bufA, bufB, j0, kb, g, col, wB, wA, wb, row,
           19, ob1 + 2*FDIM,  20, ob2 + 2*FDIM);
    resblk(cur, bufA, bufB, j0, kb, g, col, wB, wA, wb, row,
           0, bJ,             0, bJ);   // dummy prefetch
  }

  // energies
  {
    float wv = Wout[col];
    float ev[2][4];
    #pragma unroll
    for (int s = 0; s < 2; s++)
      #pragma unroll
      for (int i = 0; i < 4; i++) ev[s][i] = sp_f(cur[s][i]) * wv;
    #pragma unroll
    for (int off = 1; off < 16; off <<= 1){
      #pragma unroll
      for (int s = 0; s < 2; s++)
        #pragma unroll
        for (int i = 0; i < 4; i++) ev[s][i] += __shfl_xor(ev[s][i], off);
    }
    if (j0 == 0){
      #pragma unroll
      for (int s = 0; s < 2; s++)
        #pragma unroll
        for (int i = 0; i < 4; i++) evp[nt][16*s + g*4 + i] = ev[s][i];
    }
  }
  __syncthreads();
  if (t < AROWS)
    out_e[base + t] = (evp[0][t] + evp[1][t] + evp[2][t] + evp[3][t] + evp[4][t]
                       + bout[0]) * mskl[t];
}

// ---------------------------------------------------------------------------
extern "C" void kernel_launch(void* const* d_in, const int* in_sizes, int n_in,
                              void* d_out, int out_size, void* d_ws, size_t ws_size,
                              hipStream_t stream) {
  const int*   species  = (const int*)  d_in[0];
  const float* features = (const float*)d_in[1];
  const float* aev      = (const float*)d_in[2];
  const int*   idx12    = (const int*)  d_in[3];
  const float* WI   = (const float*)d_in[4];  const float* bI   = (const float*)d_in[5];
  const float* Wg   = (const float*)d_in[6];  const float* bg   = (const float*)d_in[7];
  const float* WJ   = (const float*)d_in[8];  const float* bJ   = (const float*)d_in[9];
  const float* iW1  = (const float*)d_in[10]; const float* ib1  = (const float*)d_in[11];
  const float* iW2  = (const float*)d_in[12]; const float* ib2  = (const float*)d_in[13];
  const float* gate = (const float*)d_in[14];
  const float* Wint = (const float*)d_in[15]; const float* bint = (const float*)d_in[16];
  const float* aW1  = (const float*)d_in[17]; const float* ab1  = (const float*)d_in[18];
  const float* aW2  = (const float*)d_in[19]; const float* ab2  = (const float*)d_in[20];
  const float* oW1  = (const float*)d_in[21]; const float* ob1  = (const float*)d_in[22];
  const float* oW2  = (const float*)d_in[23]; const float* ob2  = (const float*)d_in[24];
  const float* Wout = (const float*)d_in[25]; const float* bout = (const float*)d_in[26];

  const int N = in_sizes[1] / FDIM;   // 16384
  const int P = in_sizes[2] / RDIM;   // 393216

  float* out_e = (float*)d_out;
  float* out_f = out_e + N;

  const size_t REC_BYTES = (size_t)NBUCK * BCAP * (RECW * 4);
  const size_t WT_BYTES  = (size_t)21 * FDIM * WROW * sizeof(__hip_bfloat16);
  const size_t RF_BYTES  = (size_t)N * 21 * sizeof(float);
  const size_t need = REC_BYTES + RF_BYTES + WT_BYTES + NBUCK * sizeof(int);

  WPtrs wp;
  wp.p[0] = WJ; wp.p[1] = WI; wp.p[2] = Wint;
  for (int ir = 0; ir < 3; ir++){
    wp.p[3  + 2*ir] = iW1 + ir*FDIM*FDIM; wp.p[4  + 2*ir] = iW2 + ir*FDIM*FDIM;
    wp.p[9  + 2*ir] = aW1 + ir*FDIM*FDIM; wp.p[10 + 2*ir] = aW2 + ir*FDIM*FDIM;
    wp.p[15 + 2*ir] = oW1 + ir*FDIM*FDIM; wp.p[16 + 2*ir] = oW2 + ir*FDIM*FDIM;
  }

  if (ws_size >= need){
    unsigned int* rec = (unsigned int*)d_ws;
    float* Rf = (float*)((char*)d_ws + REC_BYTES);
    __hip_bfloat16* wt = (__hip_bfloat16*)((char*)Rf + RF_BYTES);
    int* gcursor = (int*)((char*)wt + WT_BYTES);

    hipMemsetAsync(gcursor, 0, NBUCK * sizeof(int), stream);
    prep_weights<<<21, 256, 0, stream>>>(wp, wt);
    binA<<<(2 * P) / CHUNK, 256, 0, stream>>>(aev, idx12, gcursor, rec, P);
    accumB<<<NBUCK, 256, 0, stream>>>(rec, gcursor, Rf);
    atom_mfma<<<(N + AROWS - 1) / AROWS, 320, 0, stream>>>(species, features, Rf, wt,
        Wg, bg, bJ, bI, ib1, ib2, gate, bint, ab1, ab2, ob1, ob2, Wout, bout,
        out_e, out_f);
  } else {
    unsigned long long* R5u = (unsigned long long*)d_ws;
    float* Rf = (float*)(R5u + (size_t)N * RSLOT);
    __hip_bfloat16* wt = (__hip_bfloat16*)((char*)Rf + RF_BYTES);

    hipMemsetAsync(R5u, 0, (size_t)N * RSLOT * sizeof(unsigned long long), stream);
    prep_weights<<<21, 256, 0, stream>>>(wp, wt);
    scatter_p13<<<((size_t)P * RSLOT + 255) / 256, 256, 0, stream>>>(aev, idx12, R5u, P);
    conv_p13<<<(N + 255) / 256, 256, 0, stream>>>(R5u, Rf, N);
    atom_mfma<<<(N + AROWS - 1) / AROWS, 320, 0, stream>>>(species, features, Rf, wt,
        Wg, bg, bJ, bI, ib1, ib2, gate, bint, ab1, ab2, ob1, ob2, Wout, bout,
        out_e, out_f);
  }
}

// Round 12
// 110.105 us; speedup vs baseline: 1.6190x; 1.6190x over previous
//
#include <hip/hip_runtime.h>
#include <hip/hip_bf16.h>

#define FDIM 80
#define RDIM 20
#define RSLOT 5      // u64 slots per atom row: 4 fields x 13 bits each + deg in slot0[52:63]
#define NXCD 8       // partitions (one per XCD)
#define LDP  104     // LDS row stride (bf16)
#define WROW 96      // Wt row stride (bf16), K padded to 96
#define AROWS 16     // atoms per block in atom_mfma

#define FIX_SCALE 64.0f     // 2^6
#define FIX_INV   0.015625f // 2^-6

typedef float  f32x4  __attribute__((ext_vector_type(4)));
typedef short  bf16x8 __attribute__((ext_vector_type(8)));

__device__ __forceinline__ float sp_f(float x){
  float e = __expf(-fabsf(x));
  return fmaxf(x, 0.f) + __logf(1.f + e);
}
__device__ __forceinline__ __hip_bfloat16 tob(float x){ return __float2bfloat16(x); }

__device__ __forceinline__ int get_xcc(){
  unsigned v;
  asm volatile("s_getreg_b32 %0, hwreg(HW_REG_XCC_ID)" : "=s"(v));
  return (int)(v & (NXCD - 1));
}

// ---------------------------------------------------------------------------
// Weight prep: Wt[slot][j][k] = bf16(W[k][j]), zero-padded k in [80,96)
// ---------------------------------------------------------------------------
struct WPtrs { const float* p[21]; };

__global__ __launch_bounds__(256) void prep_weights(WPtrs wp, __hip_bfloat16* __restrict__ wt){
  const float* W = wp.p[blockIdx.x];
  __hip_bfloat16* dst = wt + (size_t)blockIdx.x * FDIM * WROW;
  for (int i = threadIdx.x; i < FDIM * WROW; i += 256){
    int j = i / WROW, k = i - j * WROW;
    dst[i] = __float2bfloat16(k < FDIM ? W[k * FDIM + j] : 0.f);
  }
}

// ---------------------------------------------------------------------------
// Scatter, 13-bit fixed-point, XCD-partitioned L2-local atomics.
// Partition x is only ever touched by waves running on XCD x, so a
// workgroup-scope atomic (executed in the local TCC) is correct; the
// kernel-boundary release flushes dirty L2 for the consumer kernel.
// ---------------------------------------------------------------------------
__global__ __launch_bounds__(256) void scatter_xcd(const float* __restrict__ aev,
    const int* __restrict__ idx12, unsigned long long* __restrict__ R5u,
    size_t pstride, int P)
{
  int g = blockIdx.x * 256 + threadIdx.x;
  if (g >= P * RSLOT) return;
  int p = g / RSLOT, s = g - p * RSLOT;
  float4 a = ((const float4*)(aev + (size_t)p * RDIM))[s];
  unsigned long long f0 = (unsigned long long)__float2uint_rn(a.x * FIX_SCALE);
  unsigned long long f1 = (unsigned long long)__float2uint_rn(a.y * FIX_SCALE);
  unsigned long long f2 = (unsigned long long)__float2uint_rn(a.z * FIX_SCALE);
  unsigned long long f3 = (unsigned long long)__float2uint_rn(a.w * FIX_SCALE);
  unsigned long long v = f0 | (f1 << 13) | (f2 << 26) | (f3 << 39);
  if (s == 0) v |= (1ULL << 52);   // deg increment
  unsigned long long* part = R5u + (size_t)get_xcc() * pstride;
  int i1 = idx12[p], i2 = idx12[P + p];
  __hip_atomic_fetch_add(&part[(size_t)i1 * RSLOT + s], v,
                         __ATOMIC_RELAXED, __HIP_MEMORY_SCOPE_WORKGROUP);
  __hip_atomic_fetch_add(&part[(size_t)i2 * RSLOT + s], v,
                         __ATOMIC_RELAXED, __HIP_MEMORY_SCOPE_WORKGROUP);
}

// ---------------------------------------------------------------------------
// Weight fragment (one layer's B-operand for this thread) + rolling prefetch
// ---------------------------------------------------------------------------
struct WF { bf16x8 b0, b1, b2; float bias; };

__device__ __forceinline__ WF loadWF(const __hip_bfloat16* __restrict__ wb,
                                     int slot, const float* __restrict__ bias, int row){
  WF w;
  const __hip_bfloat16* p = wb + (size_t)slot * (FDIM * WROW);
  w.b0 = *(const bf16x8*)(const void*)(p);
  w.b1 = *(const bf16x8*)(const void*)(p + 32);
  w.b2 = *(const bf16x8*)(const void*)(p + 64);
  w.bias = bias[row];
  return w;
}

// A-frag: m=lane&15, k=(lane>>4)*8+e (+32ks). C/D: col=lane&15, row=(lane>>4)*4+i.
__device__ __forceinline__ f32x4 mfmaL(
    const __hip_bfloat16 (*in)[LDP], int j0, int kb, const WF& w)
{
  const __hip_bfloat16* ap = &in[j0][kb];
  bf16x8 a0 = *(const bf16x8*)(const void*)(ap);
  bf16x8 a1 = *(const bf16x8*)(const void*)(ap + 32);
  bf16x8 a2 = *(const bf16x8*)(const void*)(ap + 64);
  f32x4 acc = (f32x4){w.bias, w.bias, w.bias, w.bias};
  acc = __builtin_amdgcn_mfma_f32_16x16x32_bf16(a0, w.b0, acc, 0, 0, 0);
  acc = __builtin_amdgcn_mfma_f32_16x16x32_bf16(a1, w.b1, acc, 0, 0, 0);
  acc = __builtin_amdgcn_mfma_f32_16x16x32_bf16(a2, w.b2, acc, 0, 0, 0);
  return acc;
}

// One residual block: uses preloaded w1,w2; prefetches pf1->w1, pf2->w2.
__device__ __forceinline__ void resblk(f32x4& cur,
    __hip_bfloat16 (*bA)[LDP], __hip_bfloat16 (*bB)[LDP],
    int j0, int kb, int g, int col,
    WF& w1, WF& w2,
    const __hip_bfloat16* __restrict__ wb, int row,
    int pf1, const float* __restrict__ pf1b,
    int pf2, const float* __restrict__ pf2b)
{
  f32x4 acc = mfmaL(bA, j0, kb, w1);
  w1 = loadWF(wb, pf1, pf1b, row);
  #pragma unroll
  for (int i = 0; i < 4; i++) bB[g*4 + i][col] = tob(sp_f(acc[i]));
  __syncthreads();
  acc = mfmaL(bB, j0, kb, w2);
  w2 = loadWF(wb, pf2, pf2b, row);
  #pragma unroll
  for (int i = 0; i < 4; i++){
    cur[i] = sp_f(acc[i] + cur[i]);
    bA[g*4 + i][col] = tob(cur[i]);
  }
  __syncthreads();
}

// ---------------------------------------------------------------------------
// Atom kernel: 16 atoms/block, 5 waves (one 16-col block each); S computed
// in-kernel from the 8 summed R5u partitions; rolling weight prefetch.
// ---------------------------------------------------------------------------
__global__ __launch_bounds__(320, 4) void atom_mfma(
    const int*   __restrict__ species,
    const float* __restrict__ features,
    const unsigned long long* __restrict__ R5u, size_t pstride,
    const __hip_bfloat16* __restrict__ wt,
    const float* __restrict__ Wg, const float* __restrict__ bg,
    const float* __restrict__ bJ, const float* __restrict__ bI,
    const float* __restrict__ ib1, const float* __restrict__ ib2,
    const float* __restrict__ gate, const float* __restrict__ bint,
    const float* __restrict__ ab1, const float* __restrict__ ab2,
    const float* __restrict__ ob1, const float* __restrict__ ob2,
    const float* __restrict__ Wout, const float* __restrict__ bout,
    float* __restrict__ out_e, float* __restrict__ out_f)
{
  __shared__ __align__(16) __hip_bfloat16 bufA[AROWS][LDP];
  __shared__ __align__(16) __hip_bfloat16 bufB[AROWS][LDP];
  __shared__ __align__(16) __hip_bfloat16 xfb[AROWS][LDP];
  __shared__ float Rl[AROWS][22];      // 0..19 aev sums, 20 deg
  __shared__ float mskl[AROWS];
  __shared__ float evp[5][AROWS];

  const int t    = threadIdx.x;
  const int lane = t & 63;
  const int nt   = t >> 6;          // 0..4 : output column block
  const int base = blockIdx.x * AROWS;

  const int j0  = lane & 15;
  const int g   = lane >> 4;
  const int kb  = g * 8;
  const int col = 16*nt + j0;
  const int row = col;                       // B-frag row == output col
  const __hip_bfloat16* wb = wt + (size_t)row * WROW + kb;

  // early: Wg column + bg for in-kernel S computation (dead after Sreg)
  float wgc[RDIM + 1];
  #pragma unroll
  for (int r = 0; r < RDIM; r++) wgc[r] = Wg[r * FDIM + col];
  wgc[RDIM] = bg[col];

  // stage features: raw bf16 -> xfb, softplus bf16 -> bufA
  for (int i = t; i < AROWS * FDIM; i += 320){
    int rr = i / FDIM, cc = i - rr * FDIM;
    float v = features[(size_t)(base + rr) * FDIM + cc];
    xfb [rr][cc] = tob(v);
    bufA[rr][cc] = tob(sp_f(v));
  }
  // zero K-pad cols [80,96)
  for (int i = t; i < 3 * AROWS * 16; i += 320){
    int b = i / (AROWS * 16), rem = i % (AROWS * 16);
    int rr = rem >> 4, cc = FDIM + (rem & 15);
    if      (b == 0) bufA[rr][cc] = tob(0.f);
    else if (b == 1) bufB[rr][cc] = tob(0.f);
    else             xfb [rr][cc] = tob(0.f);
  }
  // stage + unpack R: sum the 8 XCD partitions (no cross-field carry:
  // totals equal the pre-partition sums, field max < 2^13, deg < 2^12)
  if (t < AROWS * RSLOT){
    int u = t / RSLOT, s5 = t - u * RSLOT;
    const unsigned long long* pp = R5u + (size_t)(base + u) * RSLOT + s5;
    unsigned long long v = 0;
    #pragma unroll
    for (int x = 0; x < NXCD; x++) v += pp[(size_t)x * pstride];
    #pragma unroll
    for (int f = 0; f < 4; f++)
      Rl[u][4*s5 + f] = (float)((unsigned int)(v >> (13*f)) & 0x1fffu) * FIX_INV;
    if (s5 == 0) Rl[u][RDIM] = (float)((unsigned int)(v >> 52) & 0xfffu);
  }
  if (t < AROWS) mskl[t] = (species[base + t] != -1) ? 1.f : 0.f;
  __syncthreads();

  // S in registers: Sreg[i] for rows g*4+i, column `col`
  f32x4 Sreg;
  #pragma unroll
  for (int i = 0; i < 4; i++){
    int rr = g*4 + i;
    float a = 0.f;
    #pragma unroll
    for (int r = 0; r <= RDIM; r++) a += Rl[rr][r] * wgc[r];
    Sreg[i] = a;
  }

  f32x4 cur;

  // proto = sp(sp(f)@WJ+bJ) * S + (f@WI+bI)*mask   (layers L0,L1)
  {
    WF wA = loadWF(wb, 0, bJ, row);
    WF wB = loadWF(wb, 1, bI, row);
    f32x4 aJ = mfmaL(bufA, j0, kb, wA);  wA = loadWF(wb, 3, ib1, row);
    f32x4 aI = mfmaL(xfb , j0, kb, wB);  wB = loadWF(wb, 4, ib2, row);
    __syncthreads();   // bufA reads done before overwrite
    #pragma unroll
    for (int i = 0; i < 4; i++){
      cur[i] = sp_f(aJ[i]) * Sreg[i] + aI[i] * mskl[g*4 + i];
      bufA[g*4 + i][col] = tob(cur[i]);
    }
    __syncthreads();

    // message = res_stack(proto, iW): slots (3,4),(5,6),(7,8)
    resblk(cur, bufA, bufB, j0, kb, g, col, wA, wB, wb, row,
           5, ib1 + FDIM,     6, ib2 + FDIM);
    resblk(cur, bufA, bufB, j0, kb, g, col, wA, wB, wb, row,
           7, ib1 + 2*FDIM,   8, ib2 + 2*FDIM);
    resblk(cur, bufA, bufB, j0, kb, g, col, wA, wB, wb, row,
           2, bint,           9, ab1);

    // nd = f*gate + sp(message)@Wint + bint   (layer L8, uses wA=slot2)
    #pragma unroll
    for (int i = 0; i < 4; i++) bufB[g*4 + i][col] = tob(sp_f(cur[i]));
    __syncthreads();
    {
      f32x4 acc = mfmaL(bufB, j0, kb, wA);
      wA = loadWF(wb, 10, ab2, row);
      float gj = gate[col];
      #pragma unroll
      for (int i = 0; i < 4; i++){
        float xv = __bfloat162float(xfb[g*4 + i][col]);
        cur[i] = xv * gj + acc[i];
        bufA[g*4 + i][col] = tob(cur[i]);
      }
    }
    __syncthreads();

    // nd = res_stack(nd, aW): slots (9,10),(11,12),(13,14)  [w1=wB, w2=wA]
    resblk(cur, bufA, bufB, j0, kb, g, col, wB, wA, wb, row,
           11, ab1 + FDIM,    12, ab2 + FDIM);
    resblk(cur, bufA, bufB, j0, kb, g, col, wB, wA, wb, row,
           13, ab1 + 2*FDIM,  14, ab2 + 2*FDIM);
    resblk(cur, bufA, bufB, j0, kb, g, col, wB, wA, wb, row,
           15, ob1,           16, ob2);

    // out_features = nd * mask
    #pragma unroll
    for (int i = 0; i < 4; i++)
      out_f[(size_t)(base + g*4 + i) * FDIM + col] = cur[i] * mskl[g*4 + i];

    // t3 = res_stack(nd, oW): slots (15,16),(17,18),(19,20)
    resblk(cur, bufA, bufB, j0, kb, g, col, wB, wA, wb, row,
           17, ob1 + FDIM,    18, ob2 + FDIM);
    resblk(cur, bufA, bufB, j0, kb, g, col, wB, wA, wb, row,
           19, ob1 + 2*FDIM,  20, ob2 + 2*FDIM);
    resblk(cur, bufA, bufB, j0, kb, g, col, wB, wA, wb, row,
           0, bJ,             0, bJ);   // dummy prefetch
  }

  // energies = (sp(t3) @ Wout + bout) * mask
  {
    float wv = Wout[col];
    float ev[4];
    #pragma unroll
    for (int i = 0; i < 4; i++) ev[i] = sp_f(cur[i]) * wv;
    #pragma unroll
    for (int off = 1; off < 16; off <<= 1){
      #pragma unroll
      for (int i = 0; i < 4; i++) ev[i] += __shfl_xor(ev[i], off);
    }
    if (j0 == 0){
      #pragma unroll
      for (int i = 0; i < 4; i++) evp[nt][g*4 + i] = ev[i];
    }
  }
  __syncthreads();
  if (t < AROWS)
    out_e[base + t] = (evp[0][t] + evp[1][t] + evp[2][t] + evp[3][t] + evp[4][t]
                       + bout[0]) * mskl[t];
}

// ---------------------------------------------------------------------------
extern "C" void kernel_launch(void* const* d_in, const int* in_sizes, int n_in,
                              void* d_out, int out_size, void* d_ws, size_t ws_size,
                              hipStream_t stream) {
  const int*   species  = (const int*)  d_in[0];
  const float* features = (const float*)d_in[1];
  const float* aev      = (const float*)d_in[2];
  const int*   idx12    = (const int*)  d_in[3];
  const float* WI   = (const float*)d_in[4];  const float* bI   = (const float*)d_in[5];
  const float* Wg   = (const float*)d_in[6];  const float* bg   = (const float*)d_in[7];
  const float* WJ   = (const float*)d_in[8];  const float* bJ   = (const float*)d_in[9];
  const float* iW1  = (const float*)d_in[10]; const float* ib1  = (const float*)d_in[11];
  const float* iW2  = (const float*)d_in[12]; const float* ib2  = (const float*)d_in[13];
  const float* gate = (const float*)d_in[14];
  const float* Wint = (const float*)d_in[15]; const float* bint = (const float*)d_in[16];
  const float* aW1  = (const float*)d_in[17]; const float* ab1  = (const float*)d_in[18];
  const float* aW2  = (const float*)d_in[19]; const float* ab2  = (const float*)d_in[20];
  const float* oW1  = (const float*)d_in[21]; const float* ob1  = (const float*)d_in[22];
  const float* oW2  = (const float*)d_in[23]; const float* ob2  = (const float*)d_in[24];
  const float* Wout = (const float*)d_in[25]; const float* bout = (const float*)d_in[26];

  const int N = in_sizes[1] / FDIM;   // 16384
  const int P = in_sizes[2] / RDIM;   // 393216

  const size_t pstride = (size_t)N * RSLOT;               // u64 per partition
  unsigned long long* R5u = (unsigned long long*)d_ws;    // NXCD * N * 5 u64
  __hip_bfloat16* wt = (__hip_bfloat16*)(R5u + NXCD * pstride);  // 21*80*96 bf16

  float* out_e = (float*)d_out;
  float* out_f = out_e + N;

  hipMemsetAsync(R5u, 0, NXCD * pstride * sizeof(unsigned long long), stream);

  WPtrs wp;
  wp.p[0] = WJ; wp.p[1] = WI; wp.p[2] = Wint;
  for (int ir = 0; ir < 3; ir++){
    wp.p[3  + 2*ir] = iW1 + ir*FDIM*FDIM; wp.p[4  + 2*ir] = iW2 + ir*FDIM*FDIM;
    wp.p[9  + 2*ir] = aW1 + ir*FDIM*FDIM; wp.p[10 + 2*ir] = aW2 + ir*FDIM*FDIM;
    wp.p[15 + 2*ir] = oW1 + ir*FDIM*FDIM; wp.p[16 + 2*ir] = oW2 + ir*FDIM*FDIM;
  }
  prep_weights<<<21, 256, 0, stream>>>(wp, wt);

  scatter_xcd<<<((size_t)P * RSLOT + 255) / 256, 256, 0, stream>>>(
      aev, idx12, R5u, pstride, P);

  atom_mfma<<<(N + AROWS - 1) / AROWS, 320, 0, stream>>>(species, features,
      R5u, pstride, wt,
      Wg, bg, bJ, bI, ib1, ib2, gate, bint, ab1, ab2, ob1, ob2, Wout, bout,
      out_e, out_f);
}

// Round 13
// 110.074 us; speedup vs baseline: 1.6195x; 1.0003x over previous
//
#include <hip/hip_runtime.h>
#include <hip/hip_bf16.h>

#define FDIM 80
#define RDIM 20
#define RSLOT 5      // u64 slots per atom row: 4 fields x 13 bits each + deg in slot0[52:63]
#define NXCD 8       // partitions (one per XCD)
#define LDP  104     // LDS row stride (bf16)
#define WROW 96      // Wt row stride (bf16), K padded to 96
#define AROWS 16     // atoms per block in atom_mfma

#define FIX_SCALE 64.0f     // 2^6
#define FIX_INV   0.015625f // 2^-6

typedef float  f32x4  __attribute__((ext_vector_type(4)));
typedef short  bf16x8 __attribute__((ext_vector_type(8)));

__device__ __forceinline__ float sp_f(float x){
  float e = __expf(-fabsf(x));
  return fmaxf(x, 0.f) + __logf(1.f + e);
}
__device__ __forceinline__ __hip_bfloat16 tob(float x){ return __float2bfloat16(x); }

__device__ __forceinline__ int get_xcc(){
  unsigned v;
  asm volatile("s_getreg_b32 %0, hwreg(HW_REG_XCC_ID)" : "=s"(v));
  return (int)(v & (NXCD - 1));
}

// ---------------------------------------------------------------------------
// Weight prep: Wt[slot][j][k] = bf16(W[k][j]), zero-padded k in [80,96)
// ---------------------------------------------------------------------------
struct WPtrs { const float* p[21]; };

__global__ __launch_bounds__(256) void prep_weights(WPtrs wp, __hip_bfloat16* __restrict__ wt){
  const float* W = wp.p[blockIdx.x];
  __hip_bfloat16* dst = wt + (size_t)blockIdx.x * FDIM * WROW;
  for (int i = threadIdx.x; i < FDIM * WROW; i += 256){
    int j = i / WROW, k = i - j * WROW;
    dst[i] = __float2bfloat16(k < FDIM ? W[k * FDIM + j] : 0.f);
  }
}

// ---------------------------------------------------------------------------
// Scatter, 13-bit fixed-point, XCD-partitioned.
// EXPERIMENT: inline-asm global_atomic_add_x2 with NO sc0/sc1 cache flags =
// CU/L2-scope RMW -> executed in the local TCC, line stays dirty in L2.
// Correct because partition x is only touched from XCD x (runtime XCC_ID),
// and the end-of-dispatch agent release writes dirty L2 back for consumers.
// ---------------------------------------------------------------------------
__global__ __launch_bounds__(256) void scatter_xcd(const float* __restrict__ aev,
    const int* __restrict__ idx12, unsigned long long* __restrict__ R5u,
    size_t pstride, int P)
{
  int g = blockIdx.x * 256 + threadIdx.x;
  if (g < P * RSLOT){
    int p = g / RSLOT, s = g - p * RSLOT;
    float4 a = ((const float4*)(aev + (size_t)p * RDIM))[s];
    unsigned long long f0 = (unsigned long long)__float2uint_rn(a.x * FIX_SCALE);
    unsigned long long f1 = (unsigned long long)__float2uint_rn(a.y * FIX_SCALE);
    unsigned long long f2 = (unsigned long long)__float2uint_rn(a.z * FIX_SCALE);
    unsigned long long f3 = (unsigned long long)__float2uint_rn(a.w * FIX_SCALE);
    unsigned long long v = f0 | (f1 << 13) | (f2 << 26) | (f3 << 39);
    if (s == 0) v |= (1ULL << 52);   // deg increment
    unsigned long long* part = R5u + (size_t)get_xcc() * pstride;
    unsigned long long* a1 = &part[(size_t)idx12[p] * RSLOT + s];
    unsigned long long* a2 = &part[(size_t)idx12[P + p] * RSLOT + s];
    asm volatile("global_atomic_add_x2 %0, %1, off" :: "v"(a1), "v"(v) : "memory");
    asm volatile("global_atomic_add_x2 %0, %1, off" :: "v"(a2), "v"(v) : "memory");
  }
  // inline-asm vmem ops aren't tracked by the compiler's waitcnt insertion:
  // drain before wave exit so the dispatch-end release sees them complete.
  asm volatile("s_waitcnt vmcnt(0)" ::: "memory");
}

// ---------------------------------------------------------------------------
// Weight fragment (one layer's B-operand for this thread) + rolling prefetch
// ---------------------------------------------------------------------------
struct WF { bf16x8 b0, b1, b2; float bias; };

__device__ __forceinline__ WF loadWF(const __hip_bfloat16* __restrict__ wb,
                                     int slot, const float* __restrict__ bias, int row){
  WF w;
  const __hip_bfloat16* p = wb + (size_t)slot * (FDIM * WROW);
  w.b0 = *(const bf16x8*)(const void*)(p);
  w.b1 = *(const bf16x8*)(const void*)(p + 32);
  w.b2 = *(const bf16x8*)(const void*)(p + 64);
  w.bias = bias[row];
  return w;
}

// A-frag: m=lane&15, k=(lane>>4)*8+e (+32ks). C/D: col=lane&15, row=(lane>>4)*4+i.
__device__ __forceinline__ f32x4 mfmaL(
    const __hip_bfloat16 (*in)[LDP], int j0, int kb, const WF& w)
{
  const __hip_bfloat16* ap = &in[j0][kb];
  bf16x8 a0 = *(const bf16x8*)(const void*)(ap);
  bf16x8 a1 = *(const bf16x8*)(const void*)(ap + 32);
  bf16x8 a2 = *(const bf16x8*)(const void*)(ap + 64);
  f32x4 acc = (f32x4){w.bias, w.bias, w.bias, w.bias};
  acc = __builtin_amdgcn_mfma_f32_16x16x32_bf16(a0, w.b0, acc, 0, 0, 0);
  acc = __builtin_amdgcn_mfma_f32_16x16x32_bf16(a1, w.b1, acc, 0, 0, 0);
  acc = __builtin_amdgcn_mfma_f32_16x16x32_bf16(a2, w.b2, acc, 0, 0, 0);
  return acc;
}

// One residual block: uses preloaded w1,w2; prefetches pf1->w1, pf2->w2.
__device__ __forceinline__ void resblk(f32x4& cur,
    __hip_bfloat16 (*bA)[LDP], __hip_bfloat16 (*bB)[LDP],
    int j0, int kb, int g, int col,
    WF& w1, WF& w2,
    const __hip_bfloat16* __restrict__ wb, int row,
    int pf1, const float* __restrict__ pf1b,
    int pf2, const float* __restrict__ pf2b)
{
  f32x4 acc = mfmaL(bA, j0, kb, w1);
  w1 = loadWF(wb, pf1, pf1b, row);
  #pragma unroll
  for (int i = 0; i < 4; i++) bB[g*4 + i][col] = tob(sp_f(acc[i]));
  __syncthreads();
  acc = mfmaL(bB, j0, kb, w2);
  w2 = loadWF(wb, pf2, pf2b, row);
  #pragma unroll
  for (int i = 0; i < 4; i++){
    cur[i] = sp_f(acc[i] + cur[i]);
    bA[g*4 + i][col] = tob(cur[i]);
  }
  __syncthreads();
}

// ---------------------------------------------------------------------------
// Atom kernel: 16 atoms/block, 5 waves (one 16-col block each); S computed
// in-kernel from the 8 summed R5u partitions; rolling weight prefetch.
// ---------------------------------------------------------------------------
__global__ __launch_bounds__(320, 4) void atom_mfma(
    const int*   __restrict__ species,
    const float* __restrict__ features,
    const unsigned long long* __restrict__ R5u, size_t pstride,
    const __hip_bfloat16* __restrict__ wt,
    const float* __restrict__ Wg, const float* __restrict__ bg,
    const float* __restrict__ bJ, const float* __restrict__ bI,
    const float* __restrict__ ib1, const float* __restrict__ ib2,
    const float* __restrict__ gate, const float* __restrict__ bint,
    const float* __restrict__ ab1, const float* __restrict__ ab2,
    const float* __restrict__ ob1, const float* __restrict__ ob2,
    const float* __restrict__ Wout, const float* __restrict__ bout,
    float* __restrict__ out_e, float* __restrict__ out_f)
{
  __shared__ __align__(16) __hip_bfloat16 bufA[AROWS][LDP];
  __shared__ __align__(16) __hip_bfloat16 bufB[AROWS][LDP];
  __shared__ __align__(16) __hip_bfloat16 xfb[AROWS][LDP];
  __shared__ float Rl[AROWS][22];      // 0..19 aev sums, 20 deg
  __shared__ float mskl[AROWS];
  __shared__ float evp[5][AROWS];

  const int t    = threadIdx.x;
  const int lane = t & 63;
  const int nt   = t >> 6;          // 0..4 : output column block
  const int base = blockIdx.x * AROWS;

  const int j0  = lane & 15;
  const int g   = lane >> 4;
  const int kb  = g * 8;
  const int col = 16*nt + j0;
  const int row = col;                       // B-frag row == output col
  const __hip_bfloat16* wb = wt + (size_t)row * WROW + kb;

  // early: Wg column + bg for in-kernel S computation (dead after Sreg)
  float wgc[RDIM + 1];
  #pragma unroll
  for (int r = 0; r < RDIM; r++) wgc[r] = Wg[r * FDIM + col];
  wgc[RDIM] = bg[col];

  // stage features: raw bf16 -> xfb, softplus bf16 -> bufA
  for (int i = t; i < AROWS * FDIM; i += 320){
    int rr = i / FDIM, cc = i - rr * FDIM;
    float v = features[(size_t)(base + rr) * FDIM + cc];
    xfb [rr][cc] = tob(v);
    bufA[rr][cc] = tob(sp_f(v));
  }
  // zero K-pad cols [80,96)
  for (int i = t; i < 3 * AROWS * 16; i += 320){
    int b = i / (AROWS * 16), rem = i % (AROWS * 16);
    int rr = rem >> 4, cc = FDIM + (rem & 15);
    if      (b == 0) bufA[rr][cc] = tob(0.f);
    else if (b == 1) bufB[rr][cc] = tob(0.f);
    else             xfb [rr][cc] = tob(0.f);
  }
  // stage + unpack R: sum the 8 XCD partitions (no cross-field carry:
  // totals equal the pre-partition sums, field max < 2^13, deg < 2^12)
  if (t < AROWS * RSLOT){
    int u = t / RSLOT, s5 = t - u * RSLOT;
    const unsigned long long* pp = R5u + (size_t)(base + u) * RSLOT + s5;
    unsigned long long v = 0;
    #pragma unroll
    for (int x = 0; x < NXCD; x++) v += pp[(size_t)x * pstride];
    #pragma unroll
    for (int f = 0; f < 4; f++)
      Rl[u][4*s5 + f] = (float)((unsigned int)(v >> (13*f)) & 0x1fffu) * FIX_INV;
    if (s5 == 0) Rl[u][RDIM] = (float)((unsigned int)(v >> 52) & 0xfffu);
  }
  if (t < AROWS) mskl[t] = (species[base + t] != -1) ? 1.f : 0.f;
  __syncthreads();

  // S in registers: Sreg[i] for rows g*4+i, column `col`
  f32x4 Sreg;
  #pragma unroll
  for (int i = 0; i < 4; i++){
    int rr = g*4 + i;
    float a = 0.f;
    #pragma unroll
    for (int r = 0; r <= RDIM; r++) a += Rl[rr][r] * wgc[r];
    Sreg[i] = a;
  }

  f32x4 cur;

  // proto = sp(sp(f)@WJ+bJ) * S + (f@WI+bI)*mask   (layers L0,L1)
  {
    WF wA = loadWF(wb, 0, bJ, row);
    WF wB = loadWF(wb, 1, bI, row);
    f32x4 aJ = mfmaL(bufA, j0, kb, wA);  wA = loadWF(wb, 3, ib1, row);
    f32x4 aI = mfmaL(xfb , j0, kb, wB);  wB = loadWF(wb, 4, ib2, row);
    __syncthreads();   // bufA reads done before overwrite
    #pragma unroll
    for (int i = 0; i < 4; i++){
      cur[i] = sp_f(aJ[i]) * Sreg[i] + aI[i] * mskl[g*4 + i];
      bufA[g*4 + i][col] = tob(cur[i]);
    }
    __syncthreads();

    // message = res_stack(proto, iW): slots (3,4),(5,6),(7,8)
    resblk(cur, bufA, bufB, j0, kb, g, col, wA, wB, wb, row,
           5, ib1 + FDIM,     6, ib2 + FDIM);
    resblk(cur, bufA, bufB, j0, kb, g, col, wA, wB, wb, row,
           7, ib1 + 2*FDIM,   8, ib2 + 2*FDIM);
    resblk(cur, bufA, bufB, j0, kb, g, col, wA, wB, wb, row,
           2, bint,           9, ab1);

    // nd = f*gate + sp(message)@Wint + bint   (layer L8, uses wA=slot2)
    #pragma unroll
    for (int i = 0; i < 4; i++) bufB[g*4 + i][col] = tob(sp_f(cur[i]));
    __syncthreads();
    {
      f32x4 acc = mfmaL(bufB, j0, kb, wA);
      wA = loadWF(wb, 10, ab2, row);
      float gj = gate[col];
      #pragma unroll
      for (int i = 0; i < 4; i++){
        float xv = __bfloat162float(xfb[g*4 + i][col]);
        cur[i] = xv * gj + acc[i];
        bufA[g*4 + i][col] = tob(cur[i]);
      }
    }
    __syncthreads();

    // nd = res_stack(nd, aW): slots (9,10),(11,12),(13,14)  [w1=wB, w2=wA]
    resblk(cur, bufA, bufB, j0, kb, g, col, wB, wA, wb, row,
           11, ab1 + FDIM,    12, ab2 + FDIM);
    resblk(cur, bufA, bufB, j0, kb, g, col, wB, wA, wb, row,
           13, ab1 + 2*FDIM,  14, ab2 + 2*FDIM);
    resblk(cur, bufA, bufB, j0, kb, g, col, wB, wA, wb, row,
           15, ob1,           16, ob2);

    // out_features = nd * mask
    #pragma unroll
    for (int i = 0; i < 4; i++)
      out_f[(size_t)(base + g*4 + i) * FDIM + col] = cur[i] * mskl[g*4 + i];

    // t3 = res_stack(nd, oW): slots (15,16),(17,18),(19,20)
    resblk(cur, bufA, bufB, j0, kb, g, col, wB, wA, wb, row,
           17, ob1 + FDIM,    18, ob2 + FDIM);
    resblk(cur, bufA, bufB, j0, kb, g, col, wB, wA, wb, row,
           19, ob1 + 2*FDIM,  20, ob2 + 2*FDIM);
    resblk(cur, bufA, bufB, j0, kb, g, col, wB, wA, wb, row,
           0, bJ,             0, bJ);   // dummy prefetch
  }

  // energies = (sp(t3) @ Wout + bout) * mask
  {
    float wv = Wout[col];
    float ev[4];
    #pragma unroll
    for (int i = 0; i < 4; i++) ev[i] = sp_f(cur[i]) * wv;
    #pragma unroll
    for (int off = 1; off < 16; off <<= 1){
      #pragma unroll
      for (int i = 0; i < 4; i++) ev[i] += __shfl_xor(ev[i], off);
    }
    if (j0 == 0){
      #pragma unroll
      for (int i = 0; i < 4; i++) evp[nt][g*4 + i] = ev[i];
    }
  }
  __syncthreads();
  if (t < AROWS)
    out_e[base + t] = (evp[0][t] + evp[1][t] + evp[2][t] + evp[3][t] + evp[4][t]
                       + bout[0]) * mskl[t];
}

// ---------------------------------------------------------------------------
extern "C" void kernel_launch(void* const* d_in, const int* in_sizes, int n_in,
                              void* d_out, int out_size, void* d_ws, size_t ws_size,
                              hipStream_t stream) {
  const int*   species  = (const int*)  d_in[0];
  const float* features = (const float*)d_in[1];
  const float* aev      = (const float*)d_in[2];
  const int*   idx12    = (const int*)  d_in[3];
  const float* WI   = (const float*)d_in[4];  const float* bI   = (const float*)d_in[5];
  const float* Wg   = (const float*)d_in[6];  const float* bg   = (const float*)d_in[7];
  const float* WJ   = (const float*)d_in[8];  const float* bJ   = (const float*)d_in[9];
  const float* iW1  = (const float*)d_in[10]; const float* ib1  = (const float*)d_in[11];
  const float* iW2  = (const float*)d_in[12]; const float* ib2  = (const float*)d_in[13];
  const float* gate = (const float*)d_in[14];
  const float* Wint = (const float*)d_in[15]; const float* bint = (const float*)d_in[16];
  const float* aW1  = (const float*)d_in[17]; const float* ab1  = (const float*)d_in[18];
  const float* aW2  = (const float*)d_in[19]; const float* ab2  = (const float*)d_in[20];
  const float* oW1  = (const float*)d_in[21]; const float* ob1  = (const float*)d_in[22];
  const float* oW2  = (const float*)d_in[23]; const float* ob2  = (const float*)d_in[24];
  const float* Wout = (const float*)d_in[25]; const float* bout = (const float*)d_in[26];

  const int N = in_sizes[1] / FDIM;   // 16384
  const int P = in_sizes[2] / RDIM;   // 393216

  const size_t pstride = (size_t)N * RSLOT;               // u64 per partition
  unsigned long long* R5u = (unsigned long long*)d_ws;    // NXCD * N * 5 u64
  __hip_bfloat16* wt = (__hip_bfloat16*)(R5u + NXCD * pstride);  // 21*80*96 bf16

  float* out_e = (float*)d_out;
  float* out_f = out_e + N;

  hipMemsetAsync(R5u, 0, NXCD * pstride * sizeof(unsigned long long), stream);

  WPtrs wp;
  wp.p[0] = WJ; wp.p[1] = WI; wp.p[2] = Wint;
  for (int ir = 0; ir < 3; ir++){
    wp.p[3  + 2*ir] = iW1 + ir*FDIM*FDIM; wp.p[4  + 2*ir] = iW2 + ir*FDIM*FDIM;
    wp.p[9  + 2*ir] = aW1 + ir*FDIM*FDIM; wp.p[10 + 2*ir] = aW2 + ir*FDIM*FDIM;
    wp.p[15 + 2*ir] = oW1 + ir*FDIM*FDIM; wp.p[16 + 2*ir] = oW2 + ir*FDIM*FDIM;
  }
  prep_weights<<<21, 256, 0, stream>>>(wp, wt);

  scatter_xcd<<<((size_t)P * RSLOT + 255) / 256, 256, 0, stream>>>(
      aev, idx12, R5u, pstride, P);

  atom_mfma<<<(N + AROWS - 1) / AROWS, 320, 0, stream>>>(species, features,
      R5u, pstride, wt,
      Wg, bg, bJ, bI, ib1, ib2, gate, bint, ab1, ab2, ob1, ob2, Wout, bout,
      out_e, out_f);
}

// Round 14
// 105.905 us; speedup vs baseline: 1.6833x; 1.0394x over previous
//
#include <hip/hip_runtime.h>
#include <hip/hip_bf16.h>

#define FDIM 80
#define RDIM 20
#define RSLOT 5      // u64 slots per atom row: 4 fields x 13 bits each + deg in slot0[52:63]
#define LDP  104     // LDS row stride (bf16)
#define WROW 96      // Wt row stride (bf16), K padded to 96
#define AROWS 32     // atoms per block in atom_mfma

#define FIX_SCALE 64.0f     // 2^6
#define FIX_INV   0.015625f // 2^-6

typedef float  f32x4  __attribute__((ext_vector_type(4)));
typedef short  bf16x8 __attribute__((ext_vector_type(8)));

__device__ __forceinline__ float sp_f(float x){
  float e = __expf(-fabsf(x));
  return fmaxf(x, 0.f) + __logf(1.f + e);
}
__device__ __forceinline__ __hip_bfloat16 tob(float x){ return __float2bfloat16(x); }

// ---------------------------------------------------------------------------
// Weight prep: Wt[slot][j][k] = bf16(W[k][j]), zero-padded k in [80,96)
// ---------------------------------------------------------------------------
struct WPtrs { const float* p[21]; };

__global__ __launch_bounds__(256) void prep_weights(WPtrs wp, __hip_bfloat16* __restrict__ wt){
  const float* W = wp.p[blockIdx.x];
  __hip_bfloat16* dst = wt + (size_t)blockIdx.x * FDIM * WROW;
  for (int i = threadIdx.x; i < FDIM * WROW; i += 256){
    int j = i / WROW, k = i - j * WROW;
    dst[i] = __float2bfloat16(k < FDIM ? W[k * FDIM + j] : 0.f);
  }
}

// ---------------------------------------------------------------------------
// Scatter, 13-bit fixed-point, 4 fields per u64; deg folded into slot0[52:63].
// At the memory-side-atomic floor: 2P random row-touches x ~64B line each
// (~51 MB @ ~0.9 TB/s ~ 57us) — invariant to op width/scope/flags
// (verified rounds 4,6,7,10,12,13).
// ---------------------------------------------------------------------------
__global__ __launch_bounds__(256) void scatter_p13(const float* __restrict__ aev,
    const int* __restrict__ idx12, unsigned long long* __restrict__ R5u, int P)
{
  int g = blockIdx.x * 256 + threadIdx.x;
  if (g >= P * RSLOT) return;
  int p = g / RSLOT, s = g - p * RSLOT;
  float4 a = ((const float4*)(aev + (size_t)p * RDIM))[s];
  unsigned long long f0 = (unsigned long long)__float2uint_rn(a.x * FIX_SCALE);
  unsigned long long f1 = (unsigned long long)__float2uint_rn(a.y * FIX_SCALE);
  unsigned long long f2 = (unsigned long long)__float2uint_rn(a.z * FIX_SCALE);
  unsigned long long f3 = (unsigned long long)__float2uint_rn(a.w * FIX_SCALE);
  unsigned long long v = f0 | (f1 << 13) | (f2 << 26) | (f3 << 39);
  if (s == 0) v |= (1ULL << 52);   // deg increment
  int i1 = idx12[p], i2 = idx12[P + p];
  atomicAdd(&R5u[(size_t)i1 * RSLOT + s], v);
  atomicAdd(&R5u[(size_t)i2 * RSLOT + s], v);
}

// ---------------------------------------------------------------------------
// Weight fragment (one layer's B-operand for this thread) + rolling prefetch
// ---------------------------------------------------------------------------
struct WF { bf16x8 b0, b1, b2; float bias; };

__device__ __forceinline__ WF loadWF(const __hip_bfloat16* __restrict__ wb,
                                     int slot, const float* __restrict__ bias, int row){
  WF w;
  const __hip_bfloat16* p = wb + (size_t)slot * (FDIM * WROW);
  w.b0 = *(const bf16x8*)(const void*)(p);
  w.b1 = *(const bf16x8*)(const void*)(p + 32);
  w.b2 = *(const bf16x8*)(const void*)(p + 64);
  w.bias = bias[row];
  return w;
}

// A-frag: m=lane&15, k=(lane>>4)*8+e (+32ks). C/D: col=lane&15, row=(lane>>4)*4+i.
__device__ __forceinline__ void mfmaL(f32x4 acc[2],
    const __hip_bfloat16 (*in)[LDP], int j0, int kb, const WF& w)
{
  #pragma unroll
  for (int s = 0; s < 2; s++){
    const __hip_bfloat16* ap = &in[16*s + j0][kb];
    bf16x8 a0 = *(const bf16x8*)(const void*)(ap);
    bf16x8 a1 = *(const bf16x8*)(const void*)(ap + 32);
    bf16x8 a2 = *(const bf16x8*)(const void*)(ap + 64);
    acc[s] = (f32x4){w.bias, w.bias, w.bias, w.bias};
    acc[s] = __builtin_amdgcn_mfma_f32_16x16x32_bf16(a0, w.b0, acc[s], 0, 0, 0);
    acc[s] = __builtin_amdgcn_mfma_f32_16x16x32_bf16(a1, w.b1, acc[s], 0, 0, 0);
    acc[s] = __builtin_amdgcn_mfma_f32_16x16x32_bf16(a2, w.b2, acc[s], 0, 0, 0);
  }
}

// One residual block: uses preloaded w1,w2; prefetches pf1->w1, pf2->w2.
__device__ __forceinline__ void resblk(f32x4 cur[2],
    __hip_bfloat16 (*bA)[LDP], __hip_bfloat16 (*bB)[LDP],
    int j0, int kb, int g, int col,
    WF& w1, WF& w2,
    const __hip_bfloat16* __restrict__ wb, int row,
    int pf1, const float* __restrict__ pf1b,
    int pf2, const float* __restrict__ pf2b)
{
  f32x4 acc[2];
  mfmaL(acc, bA, j0, kb, w1);
  w1 = loadWF(wb, pf1, pf1b, row);
  #pragma unroll
  for (int s = 0; s < 2; s++){
    int r0 = 16*s + g*4;
    #pragma unroll
    for (int i = 0; i < 4; i++) bB[r0 + i][col] = tob(sp_f(acc[s][i]));
  }
  __syncthreads();
  mfmaL(acc, bB, j0, kb, w2);
  w2 = loadWF(wb, pf2, pf2b, row);
  #pragma unroll
  for (int s = 0; s < 2; s++){
    int r0 = 16*s + g*4;
    #pragma unroll
    for (int i = 0; i < 4; i++){
      cur[s][i] = sp_f(acc[s][i] + cur[s][i]);
      bA[r0 + i][col] = tob(cur[s][i]);
    }
  }
  __syncthreads();
}

// ---------------------------------------------------------------------------
// Atom kernel (best measured config, R8): 32 atoms/block, 5 waves (one 16-col
// block each, 2 row strips); S computed in-kernel from R5u; rolling weight
// prefetch. grid = N/32 = 512 blocks -> 2 blocks/CU, 10 waves/CU.
// ---------------------------------------------------------------------------
__global__ __launch_bounds__(320, 4) void atom_mfma(
    const int*   __restrict__ species,
    const float* __restrict__ features,
    const unsigned long long* __restrict__ R5u,
    const __hip_bfloat16* __restrict__ wt,
    const float* __restrict__ Wg, const float* __restrict__ bg,
    const float* __restrict__ bJ, const float* __restrict__ bI,
    const float* __restrict__ ib1, const float* __restrict__ ib2,
    const float* __restrict__ gate, const float* __restrict__ bint,
    const float* __restrict__ ab1, const float* __restrict__ ab2,
    const float* __restrict__ ob1, const float* __restrict__ ob2,
    const float* __restrict__ Wout, const float* __restrict__ bout,
    float* __restrict__ out_e, float* __restrict__ out_f)
{
  __shared__ __align__(16) __hip_bfloat16 bufA[AROWS][LDP];
  __shared__ __align__(16) __hip_bfloat16 bufB[AROWS][LDP];
  __shared__ __align__(16) __hip_bfloat16 xfb[AROWS][LDP];
  __shared__ float Rl[AROWS][22];      // 0..19 aev sums, 20 deg
  __shared__ float mskl[AROWS];
  __shared__ float evp[5][AROWS];

  const int t    = threadIdx.x;
  const int lane = t & 63;
  const int nt   = t >> 6;          // 0..4 : output column block
  const int base = blockIdx.x * AROWS;

  const int j0  = lane & 15;
  const int g   = lane >> 4;
  const int kb  = g * 8;
  const int col = 16*nt + j0;
  const int row = col;                       // B-frag row == output col
  const __hip_bfloat16* wb = wt + (size_t)row * WROW + kb;

  // early: Wg column + bg for in-kernel S computation (dead after Sreg)
  float wgc[RDIM + 1];
  #pragma unroll
  for (int r = 0; r < RDIM; r++) wgc[r] = Wg[r * FDIM + col];
  wgc[RDIM] = bg[col];

  // stage features: raw bf16 -> xfb, softplus bf16 -> bufA
  for (int i = t; i < AROWS * FDIM; i += 320){
    int rr = i / FDIM, cc = i - rr * FDIM;
    float v = features[(size_t)(base + rr) * FDIM + cc];
    xfb [rr][cc] = tob(v);
    bufA[rr][cc] = tob(sp_f(v));
  }
  // zero K-pad cols [80,96)
  for (int i = t; i < 3 * AROWS * 16; i += 320){
    int b = i / (AROWS * 16), rem = i % (AROWS * 16);
    int rr = rem >> 4, cc = FDIM + (rem & 15);
    if      (b == 0) bufA[rr][cc] = tob(0.f);
    else if (b == 1) bufB[rr][cc] = tob(0.f);
    else             xfb [rr][cc] = tob(0.f);
  }
  // stage + unpack R (13-bit fields; deg in slot0[52:63])
  if (t < AROWS * RSLOT){
    int u = t / RSLOT, s5 = t - u * RSLOT;
    unsigned long long v = R5u[(size_t)(base + u) * RSLOT + s5];
    #pragma unroll
    for (int f = 0; f < 4; f++)
      Rl[u][4*s5 + f] = (float)((unsigned int)(v >> (13*f)) & 0x1fffu) * FIX_INV;
    if (s5 == 0) Rl[u][RDIM] = (float)((unsigned int)(v >> 52) & 0xfffu);
  }
  if (t < AROWS) mskl[t] = (species[base + t] != -1) ? 1.f : 0.f;
  __syncthreads();

  // S in registers: Sreg[s][i] for rows 16s+g*4+i, column `col`
  f32x4 Sreg[2];
  #pragma unroll
  for (int s = 0; s < 2; s++){
    #pragma unroll
    for (int i = 0; i < 4; i++){
      int rr = 16*s + g*4 + i;
      float a = 0.f;
      #pragma unroll
      for (int r = 0; r <= RDIM; r++) a += Rl[rr][r] * wgc[r];
      Sreg[s][i] = a;
    }
  }

  f32x4 cur[2];

  // proto = sp(sp(f)@WJ+bJ) * S + (f@WI+bI)*mask   (layers L0,L1)
  {
    WF wA = loadWF(wb, 0, bJ, row);
    WF wB = loadWF(wb, 1, bI, row);
    f32x4 aJ[2], aI[2];
    mfmaL(aJ, bufA, j0, kb, wA);  wA = loadWF(wb, 3, ib1, row);
    mfmaL(aI, xfb , j0, kb, wB);  wB = loadWF(wb, 4, ib2, row);
    __syncthreads();   // bufA reads done before overwrite
    #pragma unroll
    for (int s = 0; s < 2; s++){
      int r0 = 16*s + g*4;
      #pragma unroll
      for (int i = 0; i < 4; i++){
        cur[s][i] = sp_f(aJ[s][i]) * Sreg[s][i] + aI[s][i] * mskl[r0 + i];
        bufA[r0 + i][col] = tob(cur[s][i]);
      }
    }
    __syncthreads();

    // message = res_stack(proto, iW): slots (3,4),(5,6),(7,8)
    resblk(cur, bufA, bufB, j0, kb, g, col, wA, wB, wb, row,
           5, ib1 + FDIM,     6, ib2 + FDIM);
    resblk(cur, bufA, bufB, j0, kb, g, col, wA, wB, wb, row,
           7, ib1 + 2*FDIM,   8, ib2 + 2*FDIM);
    resblk(cur, bufA, bufB, j0, kb, g, col, wA, wB, wb, row,
           2, bint,           9, ab1);

    // nd = f*gate + sp(message)@Wint + bint   (layer L8, uses wA=slot2)
    #pragma unroll
    for (int s = 0; s < 2; s++){
      int r0 = 16*s + g*4;
      #pragma unroll
      for (int i = 0; i < 4; i++) bufB[r0 + i][col] = tob(sp_f(cur[s][i]));
    }
    __syncthreads();
    {
      f32x4 acc[2];
      mfmaL(acc, bufB, j0, kb, wA);
      wA = loadWF(wb, 10, ab2, row);
      float gj = gate[col];
      #pragma unroll
      for (int s = 0; s < 2; s++){
        int r0 = 16*s + g*4;
        #pragma unroll
        for (int i = 0; i < 4; i++){
          float xv = __bfloat162float(xfb[r0 + i][col]);
          cur[s][i] = xv * gj + acc[s][i];
          bufA[r0 + i][col] = tob(cur[s][i]);
        }
      }
    }
    __syncthreads();

    // nd = res_stack(nd, aW): slots (9,10),(11,12),(13,14)  [w1=wB, w2=wA]
    resblk(cur, bufA, bufB, j0, kb, g, col, wB, wA, wb, row,
           11, ab1 + FDIM,    12, ab2 + FDIM);
    resblk(cur, bufA, bufB, j0, kb, g, col, wB, wA, wb, row,
           13, ab1 + 2*FDIM,  14, ab2 + 2*FDIM);
    resblk(cur, bufA, bufB, j0, kb, g, col, wB, wA, wb, row,
           15, ob1,           16, ob2);

    // out_features = nd * mask
    #pragma unroll
    for (int s = 0; s < 2; s++){
      int r0 = 16*s + g*4;
      #pragma unroll
      for (int i = 0; i < 4; i++)
        out_f[(size_t)(base + r0 + i) * FDIM + col] = cur[s][i] * mskl[r0 + i];
    }

    // t3 = res_stack(nd, oW): slots (15,16),(17,18),(19,20)
    resblk(cur, bufA, bufB, j0, kb, g, col, wB, wA, wb, row,
           17, ob1 + FDIM,    18, ob2 + FDIM);
    resblk(cur, bufA, bufB, j0, kb, g, col, wB, wA, wb, row,
           19, ob1 + 2*FDIM,  20, ob2 + 2*FDIM);
    resblk(cur, bufA, bufB, j0, kb, g, col, wB, wA, wb, row,
           0, bJ,             0, bJ);   // dummy prefetch
  }

  // energies = (sp(t3) @ Wout + bout) * mask   (reduce over j0, then nt)
  {
    float wv = Wout[col];
    float ev[2][4];
    #pragma unroll
    for (int s = 0; s < 2; s++)
      #pragma unroll
      for (int i = 0; i < 4; i++) ev[s][i] = sp_f(cur[s][i]) * wv;
    #pragma unroll
    for (int off = 1; off < 16; off <<= 1){
      #pragma unroll
      for (int s = 0; s < 2; s++)
        #pragma unroll
        for (int i = 0; i < 4; i++) ev[s][i] += __shfl_xor(ev[s][i], off);
    }
    if (j0 == 0){
      #pragma unroll
      for (int s = 0; s < 2; s++)
        #pragma unroll
        for (int i = 0; i < 4; i++) evp[nt][16*s + g*4 + i] = ev[s][i];
    }
  }
  __syncthreads();
  if (t < AROWS)
    out_e[base + t] = (evp[0][t] + evp[1][t] + evp[2][t] + evp[3][t] + evp[4][t]
                       + bout[0]) * mskl[t];
}

// ---------------------------------------------------------------------------
extern "C" void kernel_launch(void* const* d_in, const int* in_sizes, int n_in,
                              void* d_out, int out_size, void* d_ws, size_t ws_size,
                              hipStream_t stream) {
  const int*   species  = (const int*)  d_in[0];
  const float* features = (const float*)d_in[1];
  const float* aev      = (const float*)d_in[2];
  const int*   idx12    = (const int*)  d_in[3];
  const float* WI   = (const float*)d_in[4];  const float* bI   = (const float*)d_in[5];
  const float* Wg   = (const float*)d_in[6];  const float* bg   = (const float*)d_in[7];
  const float* WJ   = (const float*)d_in[8];  const float* bJ   = (const float*)d_in[9];
  const float* iW1  = (const float*)d_in[10]; const float* ib1  = (const float*)d_in[11];
  const float* iW2  = (const float*)d_in[12]; const float* ib2  = (const float*)d_in[13];
  const float* gate = (const float*)d_in[14];
  const float* Wint = (const float*)d_in[15]; const float* bint = (const float*)d_in[16];
  const float* aW1  = (const float*)d_in[17]; const float* ab1  = (const float*)d_in[18];
  const float* aW2  = (const float*)d_in[19]; const float* ab2  = (const float*)d_in[20];
  const float* oW1  = (const float*)d_in[21]; const float* ob1  = (const float*)d_in[22];
  const float* oW2  = (const float*)d_in[23]; const float* ob2  = (const float*)d_in[24];
  const float* Wout = (const float*)d_in[25]; const float* bout = (const float*)d_in[26];

  const int N = in_sizes[1] / FDIM;   // 16384
  const int P = in_sizes[2] / RDIM;   // 393216

  unsigned long long* R5u = (unsigned long long*)d_ws;              // N*5 u64
  __hip_bfloat16* wt = (__hip_bfloat16*)(R5u + (size_t)N * RSLOT);  // 21*80*96 bf16

  float* out_e = (float*)d_out;
  float* out_f = out_e + N;

  hipMemsetAsync(R5u, 0, (size_t)N * RSLOT * sizeof(unsigned long long), stream);

  WPtrs wp;
  wp.p[0] = WJ; wp.p[1] = WI; wp.p[2] = Wint;
  for (int ir = 0; ir < 3; ir++){
    wp.p[3  + 2*ir] = iW1 + ir*FDIM*FDIM; wp.p[4  + 2*ir] = iW2 + ir*FDIM*FDIM;
    wp.p[9  + 2*ir] = aW1 + ir*FDIM*FDIM; wp.p[10 + 2*ir] = aW2 + ir*FDIM*FDIM;
    wp.p[15 + 2*ir] = oW1 + ir*FDIM*FDIM; wp.p[16 + 2*ir] = oW2 + ir*FDIM*FDIM;
  }
  prep_weights<<<21, 256, 0, stream>>>(wp, wt);

  scatter_p13<<<((size_t)P * RSLOT + 255) / 256, 256, 0, stream>>>(aev, idx12, R5u, P);

  atom_mfma<<<(N + AROWS - 1) / AROWS, 320, 0, stream>>>(species, features, R5u, wt,
      Wg, bg, bJ, bI, ib1, ib2, gate, bint, ab1, ab2, ob1, ob2, Wout, bout,
      out_e, out_f);
}